// Round 5
// baseline (222.523 us; speedup 1.0000x reference)
//
#include <hip/hip_runtime.h>

// DepthDeformConv — round 5: K-split for 2x wave concurrency.
//   Round 4 lesson: manual pipelining regressed (compiler spilled hoisted
//   state, VGPR 84, occupancy 22%). Revert to round-3-style streaming body,
//   attack latency with MORE WAVES instead: each wave handles half the K
//   dimension (kv = channel half, all 9 taps) -> 8192 waves = 8/SIMD
//   (launch_bounds(256,8) caps VGPR at 64; round-3 body needed 52).
//   Block = 256 thr = 2 pixel-groups x 2 kv-waves; kv=1 writes partial acc
//   to LDS, kv=0 adds + bias + stores.

typedef __attribute__((ext_vector_type(8))) short bf16x8;
typedef __attribute__((ext_vector_type(4))) float f32x4;
typedef __attribute__((ext_vector_type(4))) unsigned int u32x4;

#define HH 128
#define WW 128
#define CC 64
#define OO 64
#define HW (128 * 128)

__device__ __forceinline__ unsigned f32_to_bf16_rne(float f) {
    unsigned u = __float_as_uint(f);
    return (u + 0x7FFFu + ((u >> 16) & 1u)) >> 16;
}

// ---------------- kernel 1: transpose+pack ----------------
__global__ __launch_bounds__(256)
void prep_kernel(const float* __restrict__ input,
                 const float* __restrict__ weight,
                 unsigned short* __restrict__ nhwc,
                 unsigned short* __restrict__ wT)
{
    const int tid = threadIdx.x;
    const int blk = blockIdx.x;
    if (blk < 1024) {
        // one block per (b, y, x-half): 64c x 64x tile via LDS
        __shared__ unsigned tile[64][65];
        const int b  = blk >> 8;
        const int y  = (blk >> 1) & 127;
        const int xbase = (blk & 1) * 64;
        #pragma unroll
        for (int it = 0; it < 16; ++it) {
            int flat = it * 256 + tid;          // 0..4095
            int c = flat >> 6, x = flat & 63;
            float v = input[((b * 64 + c) * 128 + y) * 128 + xbase + x];
            tile[c][x] = f32_to_bf16_rne(v);
        }
        __syncthreads();
        #pragma unroll
        for (int it = 0; it < 2; ++it) {
            int item = it * 256 + tid;          // 0..511
            int x = item >> 3, cg = item & 7;   // cg = 8-channel group
            unsigned r0 = tile[cg * 8 + 0][x], r1 = tile[cg * 8 + 1][x];
            unsigned r2 = tile[cg * 8 + 2][x], r3 = tile[cg * 8 + 3][x];
            unsigned r4 = tile[cg * 8 + 4][x], r5 = tile[cg * 8 + 5][x];
            unsigned r6 = tile[cg * 8 + 6][x], r7 = tile[cg * 8 + 7][x];
            u32x4 pk;
            pk[0] = r0 | (r1 << 16); pk[1] = r2 | (r3 << 16);
            pk[2] = r4 | (r5 << 16); pk[3] = r6 | (r7 << 16);
            *(u32x4*)(nhwc + ((size_t)((b * 128 + y) * 128 + xbase + x)) * 64 + cg * 8) = pk;
        }
    } else {
        // weight repack, division-free: one block per o.
        // wT[o*576 + kt*64 + c] = weight[o*576 + c*9 + kt]
        const int o = blk - 1024;               // 0..63
        #pragma unroll
        for (int it = 0; it < 3; ++it) {
            int r = it * 256 + tid;             // 0..767
            if (r < 576) {
                int kt = r >> 6, c = r & 63;
                wT[o * 576 + r] =
                    (unsigned short)f32_to_bf16_rne(weight[o * 576 + c * 9 + kt]);
            }
        }
    }
}

// ---------------- kernel 2: fused sample + MFMA, K-split ----------------
__global__ __launch_bounds__(256, 8)
void ddc_mfma(const unsigned short* __restrict__ nhwc,
              const unsigned short* __restrict__ wT,
              const float* __restrict__ offset,
              const float* __restrict__ mask,
              const float* __restrict__ bias,
              float* __restrict__ out)
{
    const int blk  = blockIdx.x;           // 2048 = 4b * 128h * 4 quarters
    const int b    = blk >> 9;
    const int h    = (blk >> 2) & 127;
    const int q    = blk & 3;
    const int tid  = threadIdx.x;
    const int wave = tid >> 6;
    const int lane = tid & 63;
    const int pg   = wave & 1;             // pixel group within block
    const int kv   = wave >> 1;            // K half (channel 0-31 / 32-63)
    const int l15  = lane & 15;            // pixel within group / o-col
    const int kq   = lane >> 4;            // k-chunk quad (0..3)
    const int wpix = q * 32 + pg * 16 + l15;
    const int coff = kv * 32 + kq * 8;     // this lane's channel chunk

    __shared__ float red[2][16][68];       // partial-acc exchange (8.7 KB)

    f32x4 acc[4];
    #pragma unroll
    for (int mt = 0; mt < 4; ++mt) acc[mt] = (f32x4){0.f, 0.f, 0.f, 0.f};

    const unsigned short* nb = nhwc + (size_t)b * HW * CC;

    #pragma unroll
    for (int kt = 0; kt < 9; ++kt) {
        // ---- stencil for (pixel, tap) ----
        const float oy = offset[((b * 18 + 2 * kt)     * 128 + h) * 128 + wpix];
        const float ox = offset[((b * 18 + 2 * kt + 1) * 128 + h) * 128 + wpix];
        const float m  = mask  [((b * 9  + kt)         * 128 + h) * 128 + wpix];
        const float py = (float)(h - 1 + kt / 3) + oy;
        const float px = (float)(wpix - 1 + kt % 3) + ox;
        const float y0f = floorf(py), x0f = floorf(px);
        const int y0 = (int)y0f, x0 = (int)x0f;
        const float wy = py - y0f, wx = px - x0f;
        const int y1 = y0 + 1, x1 = x0 + 1;
        const bool vy0 = (y0 >= 0) & (y0 < HH);
        const bool vy1 = (y1 >= 0) & (y1 < HH);
        const bool vx0 = (x0 >= 0) & (x0 < WW);
        const bool vx1 = (x1 >= 0) & (x1 < WW);
        const int y0c = min(max(y0, 0), HH - 1), y1c = min(max(y1, 0), HH - 1);
        const int x0c = min(max(x0, 0), WW - 1), x1c = min(max(x1, 0), WW - 1);
        const float wy1 = 1.f - wy, wx1 = 1.f - wx;
        const float c00 = (vy0 && vx0) ? wy1 * wx1 * m : 0.f;
        const float c01 = (vy0 && vx1) ? wy1 * wx  * m : 0.f;
        const float c10 = (vy1 && vx0) ? wy  * wx1 * m : 0.f;
        const float c11 = (vy1 && vx1) ? wy  * wx  * m : 0.f;

        // ---- 4 corner loads: 8 contiguous bf16 each ----
        const u32x4 w00 = *(const u32x4*)(nb + (y0c * WW + x0c) * CC + coff);
        const u32x4 w01 = *(const u32x4*)(nb + (y0c * WW + x1c) * CC + coff);
        const u32x4 w10 = *(const u32x4*)(nb + (y1c * WW + x0c) * CC + coff);
        const u32x4 w11 = *(const u32x4*)(nb + (y1c * WW + x1c) * CC + coff);

        // ---- unpack + weighted sum + pack -> B-fragment ----
        u32x4 pk;
        #pragma unroll
        for (int j = 0; j < 4; ++j) {
            const float a0 = __uint_as_float(w00[j] << 16);
            const float a1 = __uint_as_float(w00[j] & 0xFFFF0000u);
            const float b0 = __uint_as_float(w01[j] << 16);
            const float b1 = __uint_as_float(w01[j] & 0xFFFF0000u);
            const float d0 = __uint_as_float(w10[j] << 16);
            const float d1 = __uint_as_float(w10[j] & 0xFFFF0000u);
            const float e0 = __uint_as_float(w11[j] << 16);
            const float e1 = __uint_as_float(w11[j] & 0xFFFF0000u);
            const float s0 = c00 * a0 + c01 * b0 + c10 * d0 + c11 * e0;
            const float s1 = c00 * a1 + c01 * b1 + c10 * d1 + c11 * e1;
            pk[j] = f32_to_bf16_rne(s0) | (f32_to_bf16_rne(s1) << 16);
        }
        const bf16x8 bfrag = __builtin_bit_cast(bf16x8, pk);

        // ---- weight A-fragments + MFMA (m=o, n=pixel, k=tap/chan slice) ----
        const int kg = kt * 64 + coff;
        #pragma unroll
        for (int mt = 0; mt < 4; ++mt) {
            const bf16x8 afrag =
                *(const bf16x8*)(wT + (size_t)(mt * 16 + l15) * 576 + kg);
            acc[mt] = __builtin_amdgcn_mfma_f32_16x16x32_bf16(afrag, bfrag, acc[mt], 0, 0, 0);
        }
    }

    // ---- cross-wave K reduction + epilogue ----
    if (kv == 1) {
        #pragma unroll
        for (int mt = 0; mt < 4; ++mt) {
            *(f32x4*)&red[pg][l15][mt * 16 + kq * 4] = acc[mt];
        }
    }
    __syncthreads();
    if (kv == 0) {
        #pragma unroll
        for (int mt = 0; mt < 4; ++mt) {
            const f32x4 other = *(const f32x4*)&red[pg][l15][mt * 16 + kq * 4];
            const f32x4 bv    = *(const f32x4*)(bias + mt * 16 + kq * 4);
            #pragma unroll
            for (int r = 0; r < 4; ++r) {
                const int o = mt * 16 + kq * 4 + r;
                out[((b * 64 + o) * 128 + h) * 128 + wpix] =
                    acc[mt][r] + other[r] + bv[r];
            }
        }
    }
}

extern "C" void kernel_launch(void* const* d_in, const int* in_sizes, int n_in,
                              void* d_out, int out_size, void* d_ws, size_t ws_size,
                              hipStream_t stream)
{
    const float* input  = (const float*)d_in[0];
    // d_in[1] = depth, unused by the reference
    const float* offset = (const float*)d_in[2];
    const float* mask   = (const float*)d_in[3];
    const float* weight = (const float*)d_in[4];
    const float* bias   = (const float*)d_in[5];
    float* out = (float*)d_out;

    unsigned short* nhwc = (unsigned short*)d_ws;                    // 8.39 MB
    unsigned short* wT   = nhwc + (size_t)4 * HW * CC;               // 72 KB

    prep_kernel<<<dim3(1088), dim3(256), 0, stream>>>(input, weight, nhwc, wT);
    ddc_mfma<<<dim3(2048), dim3(256), 0, stream>>>(nhwc, wT, offset, mask, bias, out);
}

// Round 6
// 177.133 us; speedup vs baseline: 1.2562x; 1.2562x over previous
//
#include <hip/hip_runtime.h>

// DepthDeformConv — round 6: K-split with soft register budget.
//   r4 lesson: manual pipelines spill. r5 lesson: hard 64-VGPR cap spills
//   (274 MB scratch). Thesis kept: grid (4096 waves) was the limiter.
//   This round: K-split -> 8192 waves, launch_bounds(256,6) (cap 85 VGPR,
//   body ~60), 1-tap-ahead offset/mask prefetch, compiler-scheduled body.
//   Prep rebuilt as 2048 tiny transpose blocks + 64 weight blocks.

typedef __attribute__((ext_vector_type(8))) short bf16x8;
typedef __attribute__((ext_vector_type(4))) float f32x4;
typedef __attribute__((ext_vector_type(4))) unsigned int u32x4;

#define HH 128
#define WW 128
#define CC 64
#define OO 64
#define HW (128 * 128)

__device__ __forceinline__ unsigned f32_to_bf16_rne(float f) {
    unsigned u = __float_as_uint(f);
    return (u + 0x7FFFu + ((u >> 16) & 1u)) >> 16;
}

// ---------------- kernel 1: transpose+pack ----------------
__global__ __launch_bounds__(256)
void prep_kernel(const float* __restrict__ input,
                 const float* __restrict__ weight,
                 unsigned short* __restrict__ nhwc,
                 unsigned short* __restrict__ wT)
{
    const int tid = threadIdx.x;
    const int blk = blockIdx.x;
    if (blk < 2048) {
        // one block per (b, y, x-quarter): 64c x 32x tile via LDS
        __shared__ unsigned tile[64][33];
        const int b  = blk >> 9;
        const int y  = (blk >> 2) & 127;
        const int xbase = (blk & 3) * 32;
        #pragma unroll
        for (int it = 0; it < 8; ++it) {
            int flat = it * 256 + tid;          // 0..2047
            int c = flat >> 5, x = flat & 31;
            float v = input[((b * 64 + c) * 128 + y) * 128 + xbase + x];
            tile[c][x] = f32_to_bf16_rne(v);
        }
        __syncthreads();
        {
            int x = tid >> 3, cg = tid & 7;     // 32x * 8 channel-groups
            unsigned r0 = tile[cg * 8 + 0][x], r1 = tile[cg * 8 + 1][x];
            unsigned r2 = tile[cg * 8 + 2][x], r3 = tile[cg * 8 + 3][x];
            unsigned r4 = tile[cg * 8 + 4][x], r5 = tile[cg * 8 + 5][x];
            unsigned r6 = tile[cg * 8 + 6][x], r7 = tile[cg * 8 + 7][x];
            u32x4 pk;
            pk[0] = r0 | (r1 << 16); pk[1] = r2 | (r3 << 16);
            pk[2] = r4 | (r5 << 16); pk[3] = r6 | (r7 << 16);
            *(u32x4*)(nhwc + ((size_t)((b * 128 + y) * 128 + xbase + x)) * 64 + cg * 8) = pk;
        }
    } else {
        // weight repack, division-free: one block per o.
        // wT[o*576 + kt*64 + c] = weight[o*576 + c*9 + kt]
        const int o = blk - 2048;               // 0..63
        #pragma unroll
        for (int it = 0; it < 3; ++it) {
            int r = it * 256 + tid;             // 0..767
            if (r < 576) {
                int kt = r >> 6, c = r & 63;
                wT[o * 576 + r] =
                    (unsigned short)f32_to_bf16_rne(weight[o * 576 + c * 9 + kt]);
            }
        }
    }
}

// ---------------- kernel 2: fused sample + MFMA, K-split ----------------
__global__ __launch_bounds__(256, 6)
void ddc_mfma(const unsigned short* __restrict__ nhwc,
              const unsigned short* __restrict__ wT,
              const float* __restrict__ offset,
              const float* __restrict__ mask,
              const float* __restrict__ bias,
              float* __restrict__ out)
{
    const int blk  = blockIdx.x;           // 2048 = 4b * 128h * 4 quarters
    const int b    = blk >> 9;
    const int h    = (blk >> 2) & 127;
    const int q    = blk & 3;
    const int tid  = threadIdx.x;
    const int wave = tid >> 6;
    const int lane = tid & 63;
    const int pg   = wave & 1;             // pixel group within block
    const int kv   = wave >> 1;            // K half (channels 0-31 / 32-63)
    const int l15  = lane & 15;            // pixel within group / o-col
    const int kq   = lane >> 4;            // k-chunk quad (0..3)
    const int wpix = q * 32 + pg * 16 + l15;
    const int coff = kv * 32 + kq * 8;     // this lane's channel chunk

    __shared__ float red[2][16][68];       // partial-acc exchange (8.7 KB)

    f32x4 acc[4];
    #pragma unroll
    for (int mt = 0; mt < 4; ++mt) acc[mt] = (f32x4){0.f, 0.f, 0.f, 0.f};

    const unsigned short* nb = nhwc + (size_t)b * HW * CC;

    // offset/mask base indices for this pixel (channel stride = HW)
    const int obase = b * 18 * HW + h * 128 + wpix;
    const int mbase = b * 9  * HW + h * 128 + wpix;

    // 1-tap-ahead prefetch of offset/mask
    float oy_n = offset[obase];
    float ox_n = offset[obase + HW];
    float m_n  = mask[mbase];

    #pragma unroll
    for (int kt = 0; kt < 9; ++kt) {
        const float oy = oy_n, ox = ox_n, m = m_n;
        if (kt < 8) {
            oy_n = offset[obase + (2 * kt + 2) * HW];
            ox_n = offset[obase + (2 * kt + 3) * HW];
            m_n  = mask[mbase + (kt + 1) * HW];
        }

        // ---- stencil for (pixel, tap) ----
        const float py = (float)(h - 1 + kt / 3) + oy;
        const float px = (float)(wpix - 1 + kt % 3) + ox;
        const float y0f = floorf(py), x0f = floorf(px);
        const int y0 = (int)y0f, x0 = (int)x0f;
        const float wy = py - y0f, wx = px - x0f;
        const int y1 = y0 + 1, x1 = x0 + 1;
        const bool vy0 = (y0 >= 0) & (y0 < HH);
        const bool vy1 = (y1 >= 0) & (y1 < HH);
        const bool vx0 = (x0 >= 0) & (x0 < WW);
        const bool vx1 = (x1 >= 0) & (x1 < WW);
        const int y0c = min(max(y0, 0), HH - 1), y1c = min(max(y1, 0), HH - 1);
        const int x0c = min(max(x0, 0), WW - 1), x1c = min(max(x1, 0), WW - 1);
        const float wy1 = 1.f - wy, wx1 = 1.f - wx;
        const float c00 = (vy0 && vx0) ? wy1 * wx1 * m : 0.f;
        const float c01 = (vy0 && vx1) ? wy1 * wx  * m : 0.f;
        const float c10 = (vy1 && vx0) ? wy  * wx1 * m : 0.f;
        const float c11 = (vy1 && vx1) ? wy  * wx  * m : 0.f;

        // ---- 4 corner loads: 8 contiguous bf16 each ----
        const u32x4 w00 = *(const u32x4*)(nb + (y0c * WW + x0c) * CC + coff);
        const u32x4 w01 = *(const u32x4*)(nb + (y0c * WW + x1c) * CC + coff);
        const u32x4 w10 = *(const u32x4*)(nb + (y1c * WW + x0c) * CC + coff);
        const u32x4 w11 = *(const u32x4*)(nb + (y1c * WW + x1c) * CC + coff);

        // ---- unpack + weighted sum + pack -> B-fragment ----
        u32x4 pk;
        #pragma unroll
        for (int j = 0; j < 4; ++j) {
            const float a0 = __uint_as_float(w00[j] << 16);
            const float a1 = __uint_as_float(w00[j] & 0xFFFF0000u);
            const float b0 = __uint_as_float(w01[j] << 16);
            const float b1 = __uint_as_float(w01[j] & 0xFFFF0000u);
            const float d0 = __uint_as_float(w10[j] << 16);
            const float d1 = __uint_as_float(w10[j] & 0xFFFF0000u);
            const float e0 = __uint_as_float(w11[j] << 16);
            const float e1 = __uint_as_float(w11[j] & 0xFFFF0000u);
            const float s0 = c00 * a0 + c01 * b0 + c10 * d0 + c11 * e0;
            const float s1 = c00 * a1 + c01 * b1 + c10 * d1 + c11 * e1;
            pk[j] = f32_to_bf16_rne(s0) | (f32_to_bf16_rne(s1) << 16);
        }
        const bf16x8 bfrag = __builtin_bit_cast(bf16x8, pk);

        // ---- weight A-fragments + MFMA (m=o, n=pixel) ----
        const int kg = kt * 64 + coff;
        #pragma unroll
        for (int mt = 0; mt < 4; ++mt) {
            const bf16x8 afrag =
                *(const bf16x8*)(wT + (size_t)(mt * 16 + l15) * 576 + kg);
            acc[mt] = __builtin_amdgcn_mfma_f32_16x16x32_bf16(afrag, bfrag, acc[mt], 0, 0, 0);
        }
    }

    // ---- cross-wave K reduction + epilogue ----
    if (kv == 1) {
        #pragma unroll
        for (int mt = 0; mt < 4; ++mt) {
            *(f32x4*)&red[pg][l15][mt * 16 + kq * 4] = acc[mt];
        }
    }
    __syncthreads();
    if (kv == 0) {
        #pragma unroll
        for (int mt = 0; mt < 4; ++mt) {
            const f32x4 other = *(const f32x4*)&red[pg][l15][mt * 16 + kq * 4];
            const f32x4 bv    = *(const f32x4*)(bias + mt * 16 + kq * 4);
            #pragma unroll
            for (int r = 0; r < 4; ++r) {
                const int o = mt * 16 + kq * 4 + r;
                out[((b * 64 + o) * 128 + h) * 128 + wpix] =
                    acc[mt][r] + other[r] + bv[r];
            }
        }
    }
}

extern "C" void kernel_launch(void* const* d_in, const int* in_sizes, int n_in,
                              void* d_out, int out_size, void* d_ws, size_t ws_size,
                              hipStream_t stream)
{
    const float* input  = (const float*)d_in[0];
    // d_in[1] = depth, unused by the reference
    const float* offset = (const float*)d_in[2];
    const float* mask   = (const float*)d_in[3];
    const float* weight = (const float*)d_in[4];
    const float* bias   = (const float*)d_in[5];
    float* out = (float*)d_out;

    unsigned short* nhwc = (unsigned short*)d_ws;                    // 8.39 MB
    unsigned short* wT   = nhwc + (size_t)4 * HW * CC;               // 72 KB

    prep_kernel<<<dim3(2112), dim3(256), 0, stream>>>(input, weight, nhwc, wT);
    ddc_mfma<<<dim3(2048), dim3(256), 0, stream>>>(nhwc, wT, offset, mask, bias, out);
}

// Round 7
// 146.074 us; speedup vs baseline: 1.5234x; 1.2126x over previous
//
#include <hip/hip_runtime.h>

// DepthDeformConv — round 7: K-split, NO occupancy cap.
//   r5/r6 lesson: launch_bounds(256,{6,8}) forces the allocator to squeeze
//   arch-VGPRs (40/32) and spill to scratch (94-274 MB of WRITE traffic).
//   r3's body at plain scheduling used 52 VGPR with zero spill. So: exact
//   r3-style streaming body + K-split grid (8192 waves) + LDS reduction,
//   plain __launch_bounds__(256) — let VGPR land naturally (52-84) and get
//   6-8 waves/SIMD from the grid alone.

typedef __attribute__((ext_vector_type(8))) short bf16x8;
typedef __attribute__((ext_vector_type(4))) float f32x4;
typedef __attribute__((ext_vector_type(4))) unsigned int u32x4;

#define HH 128
#define WW 128
#define CC 64
#define OO 64
#define HW (128 * 128)

__device__ __forceinline__ unsigned f32_to_bf16_rne(float f) {
    unsigned u = __float_as_uint(f);
    return (u + 0x7FFFu + ((u >> 16) & 1u)) >> 16;
}

// ---------------- kernel 1: transpose+pack ----------------
__global__ __launch_bounds__(256)
void prep_kernel(const float* __restrict__ input,
                 const float* __restrict__ weight,
                 unsigned short* __restrict__ nhwc,
                 unsigned short* __restrict__ wT)
{
    const int tid = threadIdx.x;
    const int blk = blockIdx.x;
    if (blk < 2048) {
        // one block per (b, y, x-quarter): 64c x 32x tile via LDS
        __shared__ unsigned tile[64][33];
        const int b  = blk >> 9;
        const int y  = (blk >> 2) & 127;
        const int xbase = (blk & 3) * 32;
        #pragma unroll
        for (int it = 0; it < 8; ++it) {
            int flat = it * 256 + tid;          // 0..2047
            int c = flat >> 5, x = flat & 31;
            float v = input[((b * 64 + c) * 128 + y) * 128 + xbase + x];
            tile[c][x] = f32_to_bf16_rne(v);
        }
        __syncthreads();
        {
            int x = tid >> 3, cg = tid & 7;     // 32x * 8 channel-groups
            unsigned r0 = tile[cg * 8 + 0][x], r1 = tile[cg * 8 + 1][x];
            unsigned r2 = tile[cg * 8 + 2][x], r3 = tile[cg * 8 + 3][x];
            unsigned r4 = tile[cg * 8 + 4][x], r5 = tile[cg * 8 + 5][x];
            unsigned r6 = tile[cg * 8 + 6][x], r7 = tile[cg * 8 + 7][x];
            u32x4 pk;
            pk[0] = r0 | (r1 << 16); pk[1] = r2 | (r3 << 16);
            pk[2] = r4 | (r5 << 16); pk[3] = r6 | (r7 << 16);
            *(u32x4*)(nhwc + ((size_t)((b * 128 + y) * 128 + xbase + x)) * 64 + cg * 8) = pk;
        }
    } else {
        // weight repack, division-free: one block per o.
        // wT[o*576 + kt*64 + c] = weight[o*576 + c*9 + kt]
        const int o = blk - 2048;               // 0..63
        #pragma unroll
        for (int it = 0; it < 3; ++it) {
            int r = it * 256 + tid;             // 0..767
            if (r < 576) {
                int kt = r >> 6, c = r & 63;
                wT[o * 576 + r] =
                    (unsigned short)f32_to_bf16_rne(weight[o * 576 + c * 9 + kt]);
            }
        }
    }
}

// ---------------- kernel 2: fused sample + MFMA, K-split ----------------
__global__ __launch_bounds__(256)
void ddc_mfma(const unsigned short* __restrict__ nhwc,
              const unsigned short* __restrict__ wT,
              const float* __restrict__ offset,
              const float* __restrict__ mask,
              const float* __restrict__ bias,
              float* __restrict__ out)
{
    const int blk  = blockIdx.x;           // 2048 = 4b * 128h * 4 quarters
    const int b    = blk >> 9;
    const int h    = (blk >> 2) & 127;
    const int q    = blk & 3;
    const int tid  = threadIdx.x;
    const int wave = tid >> 6;
    const int lane = tid & 63;
    const int pg   = wave & 1;             // pixel group within block
    const int kv   = wave >> 1;            // K half (channels 0-31 / 32-63)
    const int l15  = lane & 15;            // pixel within group / o-col
    const int kq   = lane >> 4;            // k-chunk quad (0..3)
    const int wpix = q * 32 + pg * 16 + l15;
    const int coff = kv * 32 + kq * 8;     // this lane's channel chunk

    __shared__ float red[2][16][68];       // partial-acc exchange (8.7 KB)

    f32x4 acc[4];
    #pragma unroll
    for (int mt = 0; mt < 4; ++mt) acc[mt] = (f32x4){0.f, 0.f, 0.f, 0.f};

    const unsigned short* nb = nhwc + (size_t)b * HW * CC;

    #pragma unroll
    for (int kt = 0; kt < 9; ++kt) {
        // ---- stencil for (pixel, tap) ----
        const float oy = offset[((b * 18 + 2 * kt)     * 128 + h) * 128 + wpix];
        const float ox = offset[((b * 18 + 2 * kt + 1) * 128 + h) * 128 + wpix];
        const float m  = mask  [((b * 9  + kt)         * 128 + h) * 128 + wpix];
        const float py = (float)(h - 1 + kt / 3) + oy;
        const float px = (float)(wpix - 1 + kt % 3) + ox;
        const float y0f = floorf(py), x0f = floorf(px);
        const int y0 = (int)y0f, x0 = (int)x0f;
        const float wy = py - y0f, wx = px - x0f;
        const int y1 = y0 + 1, x1 = x0 + 1;
        const bool vy0 = (y0 >= 0) & (y0 < HH);
        const bool vy1 = (y1 >= 0) & (y1 < HH);
        const bool vx0 = (x0 >= 0) & (x0 < WW);
        const bool vx1 = (x1 >= 0) & (x1 < WW);
        const int y0c = min(max(y0, 0), HH - 1), y1c = min(max(y1, 0), HH - 1);
        const int x0c = min(max(x0, 0), WW - 1), x1c = min(max(x1, 0), WW - 1);
        const float wy1 = 1.f - wy, wx1 = 1.f - wx;
        const float c00 = (vy0 && vx0) ? wy1 * wx1 * m : 0.f;
        const float c01 = (vy0 && vx1) ? wy1 * wx  * m : 0.f;
        const float c10 = (vy1 && vx0) ? wy  * wx1 * m : 0.f;
        const float c11 = (vy1 && vx1) ? wy  * wx  * m : 0.f;

        // ---- 4 corner loads: 8 contiguous bf16 each ----
        const u32x4 w00 = *(const u32x4*)(nb + (y0c * WW + x0c) * CC + coff);
        const u32x4 w01 = *(const u32x4*)(nb + (y0c * WW + x1c) * CC + coff);
        const u32x4 w10 = *(const u32x4*)(nb + (y1c * WW + x0c) * CC + coff);
        const u32x4 w11 = *(const u32x4*)(nb + (y1c * WW + x1c) * CC + coff);

        // ---- unpack + weighted sum + pack -> B-fragment ----
        u32x4 pk;
        #pragma unroll
        for (int j = 0; j < 4; ++j) {
            const float a0 = __uint_as_float(w00[j] << 16);
            const float a1 = __uint_as_float(w00[j] & 0xFFFF0000u);
            const float b0 = __uint_as_float(w01[j] << 16);
            const float b1 = __uint_as_float(w01[j] & 0xFFFF0000u);
            const float d0 = __uint_as_float(w10[j] << 16);
            const float d1 = __uint_as_float(w10[j] & 0xFFFF0000u);
            const float e0 = __uint_as_float(w11[j] << 16);
            const float e1 = __uint_as_float(w11[j] & 0xFFFF0000u);
            const float s0 = c00 * a0 + c01 * b0 + c10 * d0 + c11 * e0;
            const float s1 = c00 * a1 + c01 * b1 + c10 * d1 + c11 * e1;
            pk[j] = f32_to_bf16_rne(s0) | (f32_to_bf16_rne(s1) << 16);
        }
        const bf16x8 bfrag = __builtin_bit_cast(bf16x8, pk);

        // ---- weight A-fragments + MFMA (m=o, n=pixel) ----
        const int kg = kt * 64 + coff;
        #pragma unroll
        for (int mt = 0; mt < 4; ++mt) {
            const bf16x8 afrag =
                *(const bf16x8*)(wT + (size_t)(mt * 16 + l15) * 576 + kg);
            acc[mt] = __builtin_amdgcn_mfma_f32_16x16x32_bf16(afrag, bfrag, acc[mt], 0, 0, 0);
        }
    }

    // ---- cross-wave K reduction + epilogue ----
    if (kv == 1) {
        #pragma unroll
        for (int mt = 0; mt < 4; ++mt) {
            *(f32x4*)&red[pg][l15][mt * 16 + kq * 4] = acc[mt];
        }
    }
    __syncthreads();
    if (kv == 0) {
        #pragma unroll
        for (int mt = 0; mt < 4; ++mt) {
            const f32x4 other = *(const f32x4*)&red[pg][l15][mt * 16 + kq * 4];
            const f32x4 bv    = *(const f32x4*)(bias + mt * 16 + kq * 4);
            #pragma unroll
            for (int r = 0; r < 4; ++r) {
                const int o = mt * 16 + kq * 4 + r;
                out[((b * 64 + o) * 128 + h) * 128 + wpix] =
                    acc[mt][r] + other[r] + bv[r];
            }
        }
    }
}

extern "C" void kernel_launch(void* const* d_in, const int* in_sizes, int n_in,
                              void* d_out, int out_size, void* d_ws, size_t ws_size,
                              hipStream_t stream)
{
    const float* input  = (const float*)d_in[0];
    // d_in[1] = depth, unused by the reference
    const float* offset = (const float*)d_in[2];
    const float* mask   = (const float*)d_in[3];
    const float* weight = (const float*)d_in[4];
    const float* bias   = (const float*)d_in[5];
    float* out = (float*)d_out;

    unsigned short* nhwc = (unsigned short*)d_ws;                    // 8.39 MB
    unsigned short* wT   = nhwc + (size_t)4 * HW * CC;               // 72 KB

    prep_kernel<<<dim3(2112), dim3(256), 0, stream>>>(input, weight, nhwc, wT);
    ddc_mfma<<<dim3(2048), dim3(256), 0, stream>>>(nhwc, wT, offset, mask, bias, out);
}

// Round 8
// 119.143 us; speedup vs baseline: 1.8677x; 1.2260x over previous
//
#include <hip/hip_runtime.h>

// DepthDeformConv — round 8: weight fragments from LDS, not VMEM.
//   r3 vs r7 evidence: time invariant under 2x waves / half per-wave work
//   -> bound by total divergent-VMEM request throughput. The afrag weight
//   gathers (36/wave) cost as much as the bilinear corner gathers and are
//   redundant (wT = 72 KB shared by all blocks). Fix: stage weights in LDS
//   (two 40 KB phases, static LDS < 64 KB), afrag via ds_read_b128 with an
//   even bank pattern. Block = (b,h) row: 512 thr, 8 waves x 16 px, full K
//   per wave (no kv split, no reduction). Kernels named distinctly to
//   disambiguate the persistent ~73 us total-minus-main gap.

typedef __attribute__((ext_vector_type(8))) short bf16x8;
typedef __attribute__((ext_vector_type(4))) float f32x4;
typedef __attribute__((ext_vector_type(4))) unsigned int u32x4;

#define HH 128
#define WW 128
#define CC 64
#define OO 64
#define HW (128 * 128)

__device__ __forceinline__ unsigned f32_to_bf16_rne(float f) {
    unsigned u = __float_as_uint(f);
    return (u + 0x7FFFu + ((u >> 16) & 1u)) >> 16;
}

// ---------------- kernel 1a: NCHW f32 -> NHWC bf16 ----------------
__global__ __launch_bounds__(256)
void prep_nhwc(const float* __restrict__ input,
               unsigned short* __restrict__ nhwc)
{
    // one block per (b, y, x-quarter): 64c x 32x tile via LDS
    __shared__ unsigned tile[64][33];
    const int tid = threadIdx.x;
    const int blk = blockIdx.x;
    const int b  = blk >> 9;
    const int y  = (blk >> 2) & 127;
    const int xbase = (blk & 3) * 32;
    #pragma unroll
    for (int it = 0; it < 8; ++it) {
        int flat = it * 256 + tid;          // 0..2047
        int c = flat >> 5, x = flat & 31;
        float v = input[((b * 64 + c) * 128 + y) * 128 + xbase + x];
        tile[c][x] = f32_to_bf16_rne(v);
    }
    __syncthreads();
    {
        int x = tid >> 3, cg = tid & 7;     // 32x * 8 channel-groups
        unsigned r0 = tile[cg * 8 + 0][x], r1 = tile[cg * 8 + 1][x];
        unsigned r2 = tile[cg * 8 + 2][x], r3 = tile[cg * 8 + 3][x];
        unsigned r4 = tile[cg * 8 + 4][x], r5 = tile[cg * 8 + 5][x];
        unsigned r6 = tile[cg * 8 + 6][x], r7 = tile[cg * 8 + 7][x];
        u32x4 pk;
        pk[0] = r0 | (r1 << 16); pk[1] = r2 | (r3 << 16);
        pk[2] = r4 | (r5 << 16); pk[3] = r6 | (r7 << 16);
        *(u32x4*)(nhwc + ((size_t)((b * 128 + y) * 128 + xbase + x)) * 64 + cg * 8) = pk;
    }
}

// ---------------- kernel 1b: weight -> K8-major bf16 ----------------
// wT2 as uint4[4608]: wT2[(kt*8 + c8)*64 + o] = bf16 weights for channels
// c8*8..c8*8+7 of (o, tap kt). Staging copy in the main kernel is then a
// straight coalesced memcpy.
__global__ __launch_bounds__(256)
void prep_w(const float* __restrict__ weight,
            unsigned short* __restrict__ wT2)
{
    const int d  = blockIdx.x * 256 + threadIdx.x;  // 0..4607
    const int o  = d & 63;
    const int k8 = d >> 6;                          // 0..71
    const int kt = k8 >> 3;
    const int c8 = k8 & 7;
    u32x4 pk;
    #pragma unroll
    for (int jj = 0; jj < 4; ++jj) {
        unsigned lo = f32_to_bf16_rne(weight[o * 576 + (c8 * 8 + 2 * jj)     * 9 + kt]);
        unsigned hi = f32_to_bf16_rne(weight[o * 576 + (c8 * 8 + 2 * jj + 1) * 9 + kt]);
        pk[jj] = lo | (hi << 16);
    }
    *(u32x4*)(wT2 + (size_t)d * 8) = pk;
}

// ---------------- kernel 2: fused sample + MFMA, LDS weights ----------------
__global__ __launch_bounds__(512)
void ddc_main(const unsigned short* __restrict__ nhwc,
              const unsigned short* __restrict__ wT2,
              const float* __restrict__ offset,
              const float* __restrict__ mask,
              const float* __restrict__ bias,
              float* __restrict__ out)
{
    __shared__ u32x4 wbuf[2560];           // 40 KB: tap window (5 or 4 taps)

    const int blk  = blockIdx.x;           // 512 = 4b * 128h
    const int b    = blk >> 7;
    const int h    = blk & 127;
    const int tid  = threadIdx.x;
    const int wave = tid >> 6;             // 8 pixel groups
    const int lane = tid & 63;
    const int l15  = lane & 15;            // pixel within group / o-row (A)
    const int kq   = lane >> 4;            // k-chunk quad (0..3)
    const int wpix = wave * 16 + l15;      // w coordinate (full 128 row)

    f32x4 acc[4];
    #pragma unroll
    for (int mt = 0; mt < 4; ++mt) acc[mt] = (f32x4){0.f, 0.f, 0.f, 0.f};

    const unsigned short* nb = nhwc + (size_t)b * HW * CC;
    const u32x4* wsrc = (const u32x4*)wT2;

    auto do_tap = [&](int kt, int ktl) {
        // ---- stencil for (pixel, tap) ----
        const float oy = offset[((b * 18 + 2 * kt)     * 128 + h) * 128 + wpix];
        const float ox = offset[((b * 18 + 2 * kt + 1) * 128 + h) * 128 + wpix];
        const float m  = mask  [((b * 9  + kt)         * 128 + h) * 128 + wpix];
        const float py = (float)(h - 1 + kt / 3) + oy;
        const float px = (float)(wpix - 1 + kt % 3) + ox;
        const float y0f = floorf(py), x0f = floorf(px);
        const int y0 = (int)y0f, x0 = (int)x0f;
        const float wy = py - y0f, wx = px - x0f;
        const int y1 = y0 + 1, x1 = x0 + 1;
        const bool vy0 = (y0 >= 0) & (y0 < HH);
        const bool vy1 = (y1 >= 0) & (y1 < HH);
        const bool vx0 = (x0 >= 0) & (x0 < WW);
        const bool vx1 = (x1 >= 0) & (x1 < WW);
        const int y0c = min(max(y0, 0), HH - 1), y1c = min(max(y1, 0), HH - 1);
        const int x0c = min(max(x0, 0), WW - 1), x1c = min(max(x1, 0), WW - 1);
        const float wy1 = 1.f - wy, wx1 = 1.f - wx;
        const float c00 = (vy0 && vx0) ? wy1 * wx1 * m : 0.f;
        const float c01 = (vy0 && vx1) ? wy1 * wx  * m : 0.f;
        const float c10 = (vy1 && vx0) ? wy  * wx1 * m : 0.f;
        const float c11 = (vy1 && vx1) ? wy  * wx  * m : 0.f;

        #pragma unroll
        for (int ks = 0; ks < 2; ++ks) {
            const int c0 = ks * 32 + kq * 8;   // this lane's 8-channel chunk

            const u32x4 w00 = *(const u32x4*)(nb + (y0c * WW + x0c) * CC + c0);
            const u32x4 w01 = *(const u32x4*)(nb + (y0c * WW + x1c) * CC + c0);
            const u32x4 w10 = *(const u32x4*)(nb + (y1c * WW + x0c) * CC + c0);
            const u32x4 w11 = *(const u32x4*)(nb + (y1c * WW + x1c) * CC + c0);

            u32x4 pk;
            #pragma unroll
            for (int j = 0; j < 4; ++j) {
                const float a0 = __uint_as_float(w00[j] << 16);
                const float a1 = __uint_as_float(w00[j] & 0xFFFF0000u);
                const float b0 = __uint_as_float(w01[j] << 16);
                const float b1 = __uint_as_float(w01[j] & 0xFFFF0000u);
                const float d0 = __uint_as_float(w10[j] << 16);
                const float d1 = __uint_as_float(w10[j] & 0xFFFF0000u);
                const float e0 = __uint_as_float(w11[j] << 16);
                const float e1 = __uint_as_float(w11[j] & 0xFFFF0000u);
                const float s0 = c00 * a0 + c01 * b0 + c10 * d0 + c11 * e0;
                const float s1 = c00 * a1 + c01 * b1 + c10 * d1 + c11 * e1;
                pk[j] = f32_to_bf16_rne(s0) | (f32_to_bf16_rne(s1) << 16);
            }
            const bf16x8 bfrag = __builtin_bit_cast(bf16x8, pk);

            // A-fragments from LDS (even bank pattern: 8 dword-accesses/bank)
            #pragma unroll
            for (int mt = 0; mt < 4; ++mt) {
                const bf16x8 afrag = __builtin_bit_cast(bf16x8,
                    wbuf[(ktl * 8 + ks * 4 + kq) * 64 + mt * 16 + l15]);
                acc[mt] = __builtin_amdgcn_mfma_f32_16x16x32_bf16(afrag, bfrag, acc[mt], 0, 0, 0);
            }
        }
    };

    // ---- phase 0: taps 0..4 (2560 uint4 = 40 KB) ----
    #pragma unroll
    for (int i = 0; i < 5; ++i) wbuf[i * 512 + tid] = wsrc[i * 512 + tid];
    __syncthreads();
    #pragma unroll
    for (int kt = 0; kt < 5; ++kt) do_tap(kt, kt);
    __syncthreads();

    // ---- phase 1: taps 5..8 (2048 uint4 = 32 KB) ----
    #pragma unroll
    for (int i = 0; i < 4; ++i) wbuf[i * 512 + tid] = wsrc[2560 + i * 512 + tid];
    __syncthreads();
    #pragma unroll
    for (int kt = 5; kt < 9; ++kt) do_tap(kt, kt - 5);

    // ---- epilogue: C/D layout col=lane&15 (pixel), row=kq*4+reg (o) ----
    #pragma unroll
    for (int mt = 0; mt < 4; ++mt) {
        const f32x4 bv = *(const f32x4*)(bias + mt * 16 + kq * 4);
        #pragma unroll
        for (int r = 0; r < 4; ++r) {
            const int o = mt * 16 + kq * 4 + r;
            out[((b * 64 + o) * 128 + h) * 128 + wpix] = acc[mt][r] + bv[r];
        }
    }
}

extern "C" void kernel_launch(void* const* d_in, const int* in_sizes, int n_in,
                              void* d_out, int out_size, void* d_ws, size_t ws_size,
                              hipStream_t stream)
{
    const float* input  = (const float*)d_in[0];
    // d_in[1] = depth, unused by the reference
    const float* offset = (const float*)d_in[2];
    const float* mask   = (const float*)d_in[3];
    const float* weight = (const float*)d_in[4];
    const float* bias   = (const float*)d_in[5];
    float* out = (float*)d_out;

    unsigned short* nhwc = (unsigned short*)d_ws;                    // 8.39 MB
    unsigned short* wT2  = nhwc + (size_t)4 * HW * CC;               // 73728 B

    prep_nhwc<<<dim3(2048), dim3(256), 0, stream>>>(input, nhwc);
    prep_w<<<dim3(18), dim3(256), 0, stream>>>(weight, wT2);
    ddc_main<<<dim3(512), dim3(512), 0, stream>>>(nhwc, wT2, offset, mask, bias, out);
}